// Round 5
// baseline (110.129 us; speedup 1.0000x reference)
//
#include <hip/hip_runtime.h>
#include <math.h>

// Problem shape (fixed by setup_inputs): x [B,T,D] fp32, w [D,1], b [1]
#define B  16
#define T  2048
#define D  512
#define NS 64            // segments along T
#define L  (T / NS)      // 32 rows per segment
#define D4 (D / 4)       // 128 float4 per row

__device__ __forceinline__ void fma4(float4& a, float s, const float4& v) {
    a.x = fmaf(s, v.x, a.x); a.y = fmaf(s, v.y, a.y);
    a.z = fmaf(s, v.z, a.z); a.w = fmaf(s, v.w, a.w);
}

// ---------------------------------------------------------------------------
// Single-pass decoupled-lookback kernel. 1024 blocks (ticketed), 256 thr.
// Phase 1 (no dependencies): block's 32x512 x-tile -> registers; scores,
//   segment max m_k, e_j, q_k, V_k; publish (m,q,V) + release flag.
// Lookback: wave 0 acquire-polls predecessor flags (parallel across lanes),
//   REF = max m, Qp = sum sc_j q_j, sc_sh[j] = exp(m_j-REF).
// Seed: 4 waves split sum_{j<k} sc_j V_j (L2-resident V).
// Phase 3: seeded scan over register-resident tile, write out.
// Deadlock-free: publish precedes any wait; ticket order = start order.
// ---------------------------------------------------------------------------
__global__ __launch_bounds__(256, 4) void fused_lookback(
        const float* __restrict__ x, const float* __restrict__ w,
        const float* __restrict__ bias,
        int* __restrict__ counter, int* __restrict__ flags,
        float* __restrict__ m_g, float* __restrict__ q_g,
        float* __restrict__ V, float* __restrict__ out) {
    const int tid = threadIdx.x, lane = tid & 63, wv = tid >> 6;

    __shared__ int vb_sh;
    if (tid == 0) vb_sh = atomicAdd(counter, 1);   // ticket = start order
    __syncthreads();
    const int blk = vb_sh;
    const int b = blk >> 6, k = blk & (NS - 1);
    const int t0 = k * L;

    const float4* x4 = (const float4*)x + ((size_t)b * T + t0) * D4;
    const float4* w4 = (const float4*)w;
    const float4 w0 = w4[lane], w1 = w4[lane + 64];

    // ---- Phase 1: x-tile -> registers, scores, segment softmax pieces ----
    float4 xr0[8], xr1[8];
    float dots[8];
#pragma unroll
    for (int r = 0; r < 8; ++r) {
        const int j = wv * 8 + r;
        xr0[r] = x4[(size_t)j * D4 + lane];
        xr1[r] = x4[(size_t)j * D4 + lane + 64];
        dots[r] = xr0[r].x * w0.x + xr0[r].y * w0.y + xr0[r].z * w0.z + xr0[r].w * w0.w +
                  xr1[r].x * w1.x + xr1[r].y * w1.y + xr1[r].z * w1.z + xr1[r].w * w1.w;
    }

    __shared__ float s_sh[L], e_sh[L];
    __shared__ float accbuf[4][D];
    __shared__ float sc_sh[NS];
    __shared__ float wl[L], il[L];

#pragma unroll
    for (int r = 0; r < 8; ++r) {
        float d = dots[r];
#pragma unroll
        for (int off = 32; off > 0; off >>= 1) d += __shfl_xor(d, off);
        if (lane == 0) s_sh[wv * 8 + r] = d + bias[0];
    }
    __syncthreads();

    float mk = -1e30f;
#pragma unroll
    for (int j = 0; j < L; ++j) mk = fmaxf(mk, s_sh[j]);

    float4 a0 = {0.f, 0.f, 0.f, 0.f}, a1 = {0.f, 0.f, 0.f, 0.f};
#pragma unroll
    for (int r = 0; r < 8; ++r) {
        const float e = __expf(s_sh[wv * 8 + r] - mk);
        if (lane == 0) e_sh[wv * 8 + r] = e;
        fma4(a0, e, xr0[r]); fma4(a1, e, xr1[r]);
    }
    ((float4*)accbuf[wv])[lane]      = a0;
    ((float4*)accbuf[wv])[lane + 64] = a1;
    __syncthreads();

    if (tid < 128) {
        const float4 r0 = ((float4*)accbuf[0])[tid];
        const float4 r1 = ((float4*)accbuf[1])[tid];
        const float4 r2 = ((float4*)accbuf[2])[tid];
        const float4 r3 = ((float4*)accbuf[3])[tid];
        float4 rr;
        rr.x = (r0.x + r1.x) + (r2.x + r3.x);
        rr.y = (r0.y + r1.y) + (r2.y + r3.y);
        rr.z = (r0.z + r1.z) + (r2.z + r3.z);
        rr.w = (r0.w + r1.w) + (r2.w + r3.w);
        ((float4*)V)[(size_t)blk * D4 + tid] = rr;
    }
    if (tid == 0) {
        m_g[blk] = mk;
        float q = 0.f;
#pragma unroll
        for (int j = 0; j < L; ++j) q += e_sh[j];
        q_g[blk] = q;
    }
    __syncthreads();               // all global stores of this block drained
    if (tid == 0) {
        __threadfence();           // device-scope: flush to coherence point
        __hip_atomic_store(&flags[blk], 1, __ATOMIC_RELEASE, __HIP_MEMORY_SCOPE_AGENT);
    }

    // ---- Lookback: wave 0 polls predecessors, builds scalars ----
    if (wv == 0) {
        float mj = -1e30f, qj = 0.f;
        if (lane < k) {
            while (__hip_atomic_load(&flags[b * NS + lane], __ATOMIC_ACQUIRE,
                                     __HIP_MEMORY_SCOPE_AGENT) == 0)
                __builtin_amdgcn_s_sleep(2);
            mj = m_g[b * NS + lane];
            qj = q_g[b * NS + lane];
        }
        float REF = fmaxf(mk, mj);
#pragma unroll
        for (int off = 32; off > 0; off >>= 1) REF = fmaxf(REF, __shfl_xor(REF, off));
        const float scj = (lane < k) ? __expf(mj - REF) : 0.f;
        sc_sh[lane] = scj;
        float qp = scj * qj;
#pragma unroll
        for (int off = 32; off > 0; off >>= 1) qp += __shfl_xor(qp, off);
        const float sck = __expf(mk - REF);
        // per-row weights / inverse denominators for own segment
        const float e_j = (lane < L) ? e_sh[lane] : 0.f;
        float ce = e_j;
#pragma unroll
        for (int off = 1; off < 32; off <<= 1) {
            const float t = __shfl_up(ce, off);
            if (lane >= off) ce += t;
        }
        if (lane < L) {
            wl[lane] = sck * e_j;
            il[lane] = 1.0f / fmaf(sck, ce, qp);
        }
    }
    __syncthreads();

    // ---- Seed: 4 waves split the j<k range over V ----
    float4 s0 = {0.f, 0.f, 0.f, 0.f}, s1 = {0.f, 0.f, 0.f, 0.f};
    for (int kp = wv; kp < k; kp += 4) {
        const float sc = sc_sh[kp];
        const float4* Vp = (const float4*)V + ((size_t)b * NS + kp) * D4;
        fma4(s0, sc, Vp[lane]);
        fma4(s1, sc, Vp[lane + 64]);
    }
    ((float4*)accbuf[wv])[lane]      = s0;
    ((float4*)accbuf[wv])[lane + 64] = s1;
    __syncthreads();

    float4 seed0, seed1;
    {
        const float4 c0 = ((float4*)accbuf[0])[lane];
        const float4 c1 = ((float4*)accbuf[1])[lane];
        const float4 c2 = ((float4*)accbuf[2])[lane];
        const float4 c3 = ((float4*)accbuf[3])[lane];
        seed0.x = (c0.x + c1.x) + (c2.x + c3.x);
        seed0.y = (c0.y + c1.y) + (c2.y + c3.y);
        seed0.z = (c0.z + c1.z) + (c2.z + c3.z);
        seed0.w = (c0.w + c1.w) + (c2.w + c3.w);
        const float4 d0 = ((float4*)accbuf[0])[lane + 64];
        const float4 d1 = ((float4*)accbuf[1])[lane + 64];
        const float4 d2 = ((float4*)accbuf[2])[lane + 64];
        const float4 d3 = ((float4*)accbuf[3])[lane + 64];
        seed1.x = (d0.x + d1.x) + (d2.x + d3.x);
        seed1.y = (d0.y + d1.y) + (d2.y + d3.y);
        seed1.z = (d0.z + d1.z) + (d2.z + d3.z);
        seed1.w = (d0.w + d1.w) + (d2.w + d3.w);
    }

    // ---- Phase 3: per-wave partial, LDS exchange, seeded scan, write ----
    float wcr[8], ilr[8];
    float4 t0v = {0.f, 0.f, 0.f, 0.f}, t1v = {0.f, 0.f, 0.f, 0.f};
#pragma unroll
    for (int r = 0; r < 8; ++r) {
        wcr[r] = wl[wv * 8 + r];
        ilr[r] = il[wv * 8 + r];
        fma4(t0v, wcr[r], xr0[r]); fma4(t1v, wcr[r], xr1[r]);
    }
    __syncthreads();                       // seed reads complete
    ((float4*)accbuf[wv])[lane]      = t0v;
    ((float4*)accbuf[wv])[lane + 64] = t1v;
    __syncthreads();

    float4 p0 = seed0, p1 = seed1;
    for (int w2 = 0; w2 < wv; ++w2) {      // wave-uniform loop
        const float4 c0 = ((float4*)accbuf[w2])[lane];
        const float4 c1 = ((float4*)accbuf[w2])[lane + 64];
        p0.x += c0.x; p0.y += c0.y; p0.z += c0.z; p0.w += c0.w;
        p1.x += c1.x; p1.y += c1.y; p1.z += c1.z; p1.w += c1.w;
    }

    float4* outb = (float4*)out + (size_t)b * T * D4;
    if (k == 0 && wv == 0) {               // out[b,0,:] = x[b,0,:]
        outb[lane]      = xr0[0];
        outb[lane + 64] = xr1[0];
    }
#pragma unroll
    for (int r = 0; r < 8; ++r) {
        fma4(p0, wcr[r], xr0[r]); fma4(p1, wcr[r], xr1[r]);
        const int t = t0 + wv * 8 + r;
        if (t < T - 1) {
            const float idn = ilr[r];
            float4 o0, o1;
            o0.x = p0.x * idn; o0.y = p0.y * idn; o0.z = p0.z * idn; o0.w = p0.w * idn;
            o1.x = p1.x * idn; o1.y = p1.y * idn; o1.z = p1.z * idn; o1.w = p1.w * idn;
            outb[(size_t)(t + 1) * D4 + lane]      = o0;
            outb[(size_t)(t + 1) * D4 + lane + 64] = o1;
        }
    }
}

// ---------------------------------------------------------------------------
extern "C" void kernel_launch(void* const* d_in, const int* in_sizes, int n_in,
                              void* d_out, int out_size, void* d_ws, size_t ws_size,
                              hipStream_t stream) {
    const float* x    = (const float*)d_in[0];
    const float* w    = (const float*)d_in[1];
    const float* bias = (const float*)d_in[2];
    float* out = (float*)d_out;

    // ws layout: [0,8192) bytes: counter (int @0) + flags (int[B*NS] @256B)
    //            then floats: m[B*NS] | q[B*NS] | V[B*NS*D]
    int*   counter = (int*)d_ws;
    int*   flags   = counter + 64;
    float* m_g     = (float*)((char*)d_ws + 8192);
    float* q_g     = m_g + (size_t)B * NS;
    float* V       = q_g + (size_t)B * NS;

    hipMemsetAsync(d_ws, 0, 8192, stream);   // reset ticket + flags each call
    fused_lookback<<<B * NS, 256, 0, stream>>>(x, w, bias, counter, flags,
                                               m_g, q_g, V, out);
}